// Round 5
// baseline (122.200 us; speedup 1.0000x reference)
//
#include <hip/hip_runtime.h>
#include <math.h>

// Problem constants (B=8, T=1024, H=640, N_PHONE=230, N_PHONEME=96)
#define NH 640
#define NP 230
#define NM 96
#define NROWS 8192
#define MAXL 32
#define NSTEP 20            // K-steps of 32
#define MBLK 32             // rows per block
#define NBLOCKS (NROWS / MBLK)   // 256 -> 1 block/CU, all co-resident (proven R3)
#define FRAGS_PER_BLK 80    // 20480 B-frags / 256 blocks
#define FLAG_TARGET 608u    // 256 blocks * 2 (B-share waves) + 96 (CSR waves)

// ws layout (byte offsets)
#define OFF_FLAG 0          // 4 B, zeroed by hipMemsetAsync each launch
#define OFF_CNT  512
#define OFF_CSR  4096
#define OFF_B    65536      // wsB2: 20480 frags * 16 B = 327,680 B

typedef __bf16 bf16_t;
typedef bf16_t bf16x8 __attribute__((ext_vector_type(8)));
typedef float floatx4 __attribute__((ext_vector_type(4)));

// fp32 -> bf16 round-to-nearest-even
static __device__ __forceinline__ unsigned short f2b(float f) {
    unsigned u = __float_as_uint(f);
    u += 0x7fffu + ((u >> 16) & 1u);
    return (unsigned short)(u >> 16);
}

// raw barrier: LDS-write visibility only (lgkmcnt), does NOT drain vmcnt —
// enc-half1 / B loads stay in flight across it (unlike __syncthreads).
static __device__ __forceinline__ void lds_barrier() {
    asm volatile("s_waitcnt lgkmcnt(0)" ::: "memory");
    __builtin_amdgcn_s_barrier();
    __builtin_amdgcn_sched_barrier(0);
}

// ---------------- Single regular-dispatch kernel. Phases:
//  P0 (waves 0-1): f2p loads -> bf16 B-frag share -> wsB2, RELEASE-add flag.
//     (wave 2, blocks<96): mapping -> CSR/cnt, RELEASE-add flag.
//     Producer loads are issued before enc, so the release's vmcnt drain waits
//     only ~0.5us of f2p/mapping, never the 21 MB enc stream.
//  P1 (all waves): enc half0+half1 float4 loads -> registers.
//  P2: stage half0 -> LDS (waits enc-half0 only), lds_barrier.
//  P3: spin on flag (already 608 by now) + ACQUIRE (buffer_inv -> fresh L2),
//      then csr/cnt + all-20-step B prefetch into registers.
//  P4: K0-9 on half0 (enc-half1 still in flight), stage half1, lds_barrier,
//      K10-19, epilogue seg-max + log_softmax.
// Wave wv owns a 32-col group (2 B-frags/step) across all 32 rows.
__global__ __launch_bounds__(512, 2)
void fused_all_kernel(const float* __restrict__ enc,
                      const float* __restrict__ f2p,
                      const float* __restrict__ mapping,
                      unsigned short* __restrict__ wsB2,
                      int* __restrict__ cnt,
                      int* __restrict__ csr,
                      unsigned int* __restrict__ flag,
                      float* __restrict__ out) {
    __shared__ __align__(16) unsigned short sA[2560 * 8];  // 40960 B, reused as phone[32][257]
    __shared__ int scnt[NM];
    __shared__ int scsr[NM * MAXL];      // 12288 B
    float (*phone)[257] = (float (*)[257])sA;

    const int tid  = threadIdx.x;
    const int lane = tid & 63;
    const int wv   = tid >> 6;          // 0..7 = column group (32 cols each)
    const int m16  = lane & 15;
    const int quad = lane >> 4;
    const int b    = blockIdx.x;
    const int row0 = b * MBLK;

    // ---- P0: producer waves (loads issued BEFORE enc)
    if (wv < 2) {
        int t = wv * 64 + lane;                  // 0..127
        if (t < FRAGS_PER_BLK) {
            int pg = b * FRAGS_PER_BLK + t;      // < 20480
            int m16p = pg & 15;
            int qd   = (pg >> 4) & 3;
            int ct   = (pg >> 6) & 15;
            int sp   = pg >> 10;
            int pn = ct * 16 + m16p;
            int k0 = sp * 32 + qd * 8;
            unsigned short v[8];
            #pragma unroll
            for (int j = 0; j < 8; ++j)
                v[j] = (pn < NP) ? f2b(f2p[(size_t)(k0 + j) * NP + pn]) : (unsigned short)0;
            *(uint4*)(wsB2 + (size_t)pg * 8) = *(const uint4*)v;
        }
        if (lane == 0)
            __hip_atomic_fetch_add(flag, 1u, __ATOMIC_RELEASE, __HIP_MEMORY_SCOPE_AGENT);
    } else if (wv == 2 && b < NM) {
        float mvv[4];
        #pragma unroll
        for (int c = 0; c < 4; ++c) {
            int p = c * 64 + lane;
            mvv[c] = (p < NP) ? mapping[b * NP + p] : 0.0f;
        }
        int base = 0;
        #pragma unroll
        for (int c = 0; c < 4; ++c) {
            unsigned long long mask = __ballot(mvv[c] > 0.0f);
            if (mvv[c] > 0.0f) {
                int idx = base + __popcll(mask & ((1ull << lane) - 1ull));
                if (idx < MAXL) csr[b * MAXL + idx] = c * 64 + lane;
            }
            base += __popcll(mask);
        }
        if (lane == 0) {
            cnt[b] = base < MAXL ? base : MAXL;
            __hip_atomic_fetch_add(flag, 1u, __ATOMIC_RELEASE, __HIP_MEMORY_SCOPE_AGENT);
        }
    }

    // ---- P1: enc loads, k-split halves (coalesced float4)
    float4 areg0[5], areg1[5];
    #pragma unroll
    for (int i = 0; i < 5; ++i) {
        int G = i * 8192 + tid * 16;
        int row = G / 1280;
        int cb4 = (G - row * 1280) >> 2;     // fp32 col within half, 0..319
        areg0[i] = *(const float4*)(enc + (size_t)(row0 + row) * NH + cb4);
    }
    #pragma unroll
    for (int i = 0; i < 5; ++i) {
        int G = i * 8192 + tid * 16;
        int row = G / 1280;
        int cb4 = (G - row * 1280) >> 2;
        areg1[i] = *(const float4*)(enc + (size_t)(row0 + row) * NH + 320 + cb4);
    }

    // ---- P2: stage half0 (compiler waits enc-half0 only; half1 stays in flight)
    #pragma unroll
    for (int i = 0; i < 5; ++i) {
        int G = i * 8192 + tid * 16;
        int row = G / 1280;
        int cb4 = (G - row * 1280) >> 2;
        int k = cb4;                     // half 0
        int s  = k >> 5;
        int q  = (k & 31) >> 3;
        int j0 = k & 7;                  // 0 or 4
        unsigned short v[4];
        v[0] = f2b(areg0[i].x); v[1] = f2b(areg0[i].y);
        v[2] = f2b(areg0[i].z); v[3] = f2b(areg0[i].w);
        int soff = ((s * 2 + (row >> 4)) * 64 + q * 16 + (row & 15)) * 8 + j0;
        *(uint2*)(sA + soff) = *(const uint2*)v;
    }
    lds_barrier();

    // ---- P3: flag acquire (expected no-wait) then csr/cnt + B prefetch
    while (__hip_atomic_load(flag, __ATOMIC_RELAXED, __HIP_MEMORY_SCOPE_AGENT) < FLAG_TARGET)
        __builtin_amdgcn_s_sleep(2);
    (void)__hip_atomic_load(flag, __ATOMIC_ACQUIRE, __HIP_MEMORY_SCOPE_AGENT);

    int creg[6];
    #pragma unroll
    for (int j = 0; j < 6; ++j) creg[j] = csr[tid + j * 512];
    int cc = (tid < NM) ? cnt[tid] : 0;

    const unsigned short* bptr = wsB2 + ((size_t)(wv * 2) * 64 + lane) * 8;
    uint4 bpre[2 * NSTEP];
    #pragma unroll
    for (int s = 0; s < NSTEP; ++s) {
        bpre[2 * s + 0] = *(const uint4*)(bptr + ((size_t)s * 16 + 0) * 64 * 8);
        bpre[2 * s + 1] = *(const uint4*)(bptr + ((size_t)s * 16 + 1) * 64 * 8);
    }

    // stash csr/cnt to LDS (waits only the csr loads — oldest of this batch)
    #pragma unroll
    for (int j = 0; j < 6; ++j) scsr[tid + j * 512] = creg[j];
    if (tid < NM) scnt[tid] = cc;

    floatx4 acc00 = {0.f,0.f,0.f,0.f}, acc01 = acc00, acc10 = acc00, acc11 = acc00;
    const unsigned short* aptr = sA + (size_t)lane * 8;

    // ---- P4a: K-steps 0..9 on half0 (overlaps enc-half1 HBM arrival)
    #pragma unroll
    for (int s = 0; s < 10; ++s) {
        uint4 a0 = *(const uint4*)(aptr + (size_t)(s * 2 + 0) * 64 * 8);
        uint4 a1 = *(const uint4*)(aptr + (size_t)(s * 2 + 1) * 64 * 8);
        bf16x8 A0 = __builtin_bit_cast(bf16x8, a0);
        bf16x8 A1 = __builtin_bit_cast(bf16x8, a1);
        bf16x8 B0 = __builtin_bit_cast(bf16x8, bpre[2 * s + 0]);
        bf16x8 B1 = __builtin_bit_cast(bf16x8, bpre[2 * s + 1]);
        acc00 = __builtin_amdgcn_mfma_f32_16x16x32_bf16(A0, B0, acc00, 0, 0, 0);
        acc01 = __builtin_amdgcn_mfma_f32_16x16x32_bf16(A0, B1, acc01, 0, 0, 0);
        acc10 = __builtin_amdgcn_mfma_f32_16x16x32_bf16(A1, B0, acc10, 0, 0, 0);
        acc11 = __builtin_amdgcn_mfma_f32_16x16x32_bf16(A1, B1, acc11, 0, 0, 0);
    }

    // ---- P4b: stage half1 (waits enc-half1 only; B loads are newer)
    #pragma unroll
    for (int i = 0; i < 5; ++i) {
        int G = i * 8192 + tid * 16;
        int row = G / 1280;
        int cb4 = (G - row * 1280) >> 2;
        int k = 320 + cb4;               // half 1
        int s  = k >> 5;
        int q  = (k & 31) >> 3;
        int j0 = k & 7;
        unsigned short v[4];
        v[0] = f2b(areg1[i].x); v[1] = f2b(areg1[i].y);
        v[2] = f2b(areg1[i].z); v[3] = f2b(areg1[i].w);
        int soff = ((s * 2 + (row >> 4)) * 64 + q * 16 + (row & 15)) * 8 + j0;
        *(uint2*)(sA + soff) = *(const uint2*)v;
    }
    lds_barrier();

    // ---- P4c: K-steps 10..19 on half1
    #pragma unroll
    for (int s = 10; s < NSTEP; ++s) {
        uint4 a0 = *(const uint4*)(aptr + (size_t)(s * 2 + 0) * 64 * 8);
        uint4 a1 = *(const uint4*)(aptr + (size_t)(s * 2 + 1) * 64 * 8);
        bf16x8 A0 = __builtin_bit_cast(bf16x8, a0);
        bf16x8 A1 = __builtin_bit_cast(bf16x8, a1);
        bf16x8 B0 = __builtin_bit_cast(bf16x8, bpre[2 * s + 0]);
        bf16x8 B1 = __builtin_bit_cast(bf16x8, bpre[2 * s + 1]);
        acc00 = __builtin_amdgcn_mfma_f32_16x16x32_bf16(A0, B0, acc00, 0, 0, 0);
        acc01 = __builtin_amdgcn_mfma_f32_16x16x32_bf16(A0, B1, acc01, 0, 0, 0);
        acc10 = __builtin_amdgcn_mfma_f32_16x16x32_bf16(A1, B0, acc10, 0, 0, 0);
        acc11 = __builtin_amdgcn_mfma_f32_16x16x32_bf16(A1, B1, acc11, 0, 0, 0);
    }

    __syncthreads();   // A-LDS fully consumed; safe to overwrite with phone[][]

    // C/D layout: col = lane&15, row = quad*4 + reg
    const float scale = 0.03952847075210474f;  // 1/sqrt(640)
    #pragma unroll
    for (int i = 0; i < 4; ++i) {
        int r = quad * 4 + i;
        phone[r     ][wv * 32 +  0 + m16] = acc00[i] * scale;
        phone[r     ][wv * 32 + 16 + m16] = acc01[i] * scale;
        phone[r + 16][wv * 32 +  0 + m16] = acc10[i] * scale;
        phone[r + 16][wv * 32 + 16 + m16] = acc11[i] * scale;
    }
    __syncthreads();

    // ---- seg-max + log_softmax: 16 threads per row (512 = 32 rows x 16)
    const int r   = tid >> 4;
    const int l16 = tid & 15;
    float pmv[6];
    float mx = -INFINITY;
    #pragma unroll
    for (int j = 0; j < 6; ++j) {
        int m = l16 + j * 16;
        int c = scnt[m];
        const int* lst = scsr + m * MAXL;
        float best = -INFINITY;
        for (int jj = 0; jj < c; ++jj) best = fmaxf(best, phone[r][lst[jj]]);
        pmv[j] = best;
        mx = fmaxf(mx, best);
    }
    #pragma unroll
    for (int d = 1; d < 16; d <<= 1) mx = fmaxf(mx, __shfl_xor(mx, d));
    float s = 0.f;
    #pragma unroll
    for (int j = 0; j < 6; ++j) s += __expf(pmv[j] - mx);
    #pragma unroll
    for (int d = 1; d < 16; d <<= 1) s += __shfl_xor(s, d);
    const float lse = mx + __logf(s);
    #pragma unroll
    for (int j = 0; j < 6; ++j)
        out[(size_t)(row0 + r) * NM + l16 + j * 16] = pmv[j] - lse;
}

extern "C" void kernel_launch(void* const* d_in, const int* in_sizes, int n_in,
                              void* d_out, int out_size, void* d_ws, size_t ws_size,
                              hipStream_t stream) {
    const float* enc     = (const float*)d_in[0];   // (8,1024,640) f32
    const float* f2p     = (const float*)d_in[1];   // (640,230) f32
    const float* mapping = (const float*)d_in[2];   // (96,230) f32
    float* out = (float*)d_out;                     // (8,1024,96) f32

    char* ws = (char*)d_ws;
    unsigned int* flag = (unsigned int*)(ws + OFF_FLAG);
    int* cnt = (int*)(ws + OFF_CNT);
    int* csr = (int*)(ws + OFF_CSR);
    unsigned short* wsB2 = (unsigned short*)(ws + OFF_B);

    hipMemsetAsync(ws + OFF_FLAG, 0, 4, stream);
    fused_all_kernel<<<NBLOCKS, 512, 0, stream>>>(enc, f2p, mapping, wsB2, cnt, csr, flag, out);
}

// Round 6
// 81.905 us; speedup vs baseline: 1.4920x; 1.4920x over previous
//
#include <hip/hip_runtime.h>
#include <math.h>

// Problem constants (B=8, T=1024, H=640, N_PHONE=230, N_PHONEME=96)
#define NH 640
#define NP 230
#define NM 96
#define NROWS 8192
#define MAXL 32
#define NSTEP 20            // K-steps of 32
#define MBLK 32             // rows per block
#define NBLOCKS (NROWS / MBLK)   // 256 -> 1 block/CU; >1 block/CU is useless here

// ws layout (byte offsets)
#define OFF_CNT  0
#define OFF_CSR  4096
#define OFF_B    65536      // wsB2: 20480 frags * 16 B = 327,680 B

typedef __bf16 bf16_t;
typedef bf16_t bf16x8 __attribute__((ext_vector_type(8)));
typedef float floatx4 __attribute__((ext_vector_type(4)));

// fp32 -> bf16 round-to-nearest-even
static __device__ __forceinline__ unsigned short f2b(float f) {
    unsigned u = __float_as_uint(f);
    u += 0x7fffu + ((u >> 16) & 1u);
    return (unsigned short)(u >> 16);
}

// raw barrier: LDS-write visibility only (lgkmcnt), does NOT drain vmcnt —
// in-flight global loads (enc half1, B tail) survive the barrier, unlike
// __syncthreads whose s_waitcnt vmcnt(0) voids the split-K overlap.
static __device__ __forceinline__ void lds_barrier() {
    asm volatile("s_waitcnt lgkmcnt(0)" ::: "memory");
    __builtin_amdgcn_s_barrier();
    __builtin_amdgcn_sched_barrier(0);
}

// ---------------- Prep: CSR build (blocks 0..23) + B retile (blocks 24..103)
// B frag g = (s*16+ct)*64+lane holds B^T[n=ct*16+(lane&15)][k=s*32+(lane>>4)*8+j]
__global__ __launch_bounds__(256)
void prep_kernel(const float* __restrict__ f2p,
                 const float* __restrict__ mapping,
                 int* __restrict__ cnt, int* __restrict__ csr,
                 unsigned short* __restrict__ wsB2) {
    const int b = blockIdx.x;
    const int tid = threadIdx.x;
    if (b < 24) {
        int wave = b * 4 + (tid >> 6);
        int lane = tid & 63;
        if (wave >= NM) return;
        int base = 0;
        #pragma unroll
        for (int c = 0; c < 4; ++c) {
            int p = c * 64 + lane;
            float v = (p < NP) ? mapping[wave * NP + p] : 0.0f;
            unsigned long long mask = __ballot(v > 0.0f);
            if (v > 0.0f) {
                int idx = base + __popcll(mask & ((1ull << lane) - 1ull));
                if (idx < MAXL) csr[wave * MAXL + idx] = p;
            }
            base += __popcll(mask);
        }
        if (lane == 0) cnt[wave] = base < MAXL ? base : MAXL;
    } else {
        int g = (b - 24) * 256 + tid;          // < 20480
        int m16  = g & 15;
        int quad = (g >> 4) & 3;
        int ct   = (g >> 6) & 15;
        int s    = g >> 10;
        int n = ct * 16 + m16;
        int k0 = s * 32 + quad * 8;
        unsigned short v[8];
        #pragma unroll
        for (int j = 0; j < 8; ++j)
            v[j] = (n < NP) ? f2b(f2p[(size_t)(k0 + j) * NP + n]) : (unsigned short)0;
        *(uint4*)(wsB2 + (size_t)g * 8) = *(const uint4*)v;
    }
}

// ---------------- Main: split-K pipelined A staging (half0 staged -> MFMA on
// half0 overlaps half1's HBM fetch via non-draining lds_barrier), full 20-step
// all-register B prefetch (no spill at 256-VGPR cap), fused epilogue.
// 512 thr (8 waves): wave wv owns a 32-col group (2 B-frags/step) across all
// 32 rows (2 A-frags/step, 4 accumulators); every B fragment loaded once/block.
__global__ __launch_bounds__(512, 1)
void fused_phonetics_kernel(const float* __restrict__ enc,
                            const unsigned short* __restrict__ wsB2,
                            const int* __restrict__ cnt,
                            const int* __restrict__ csr,
                            float* __restrict__ out) {
    // A frags: slot f = (s*2 + rh)*64 + lane, 8 bf16 each -> 2560*16 = 40960 B.
    // Reused as phone[32][257] floats (32896 B) in the epilogue.
    __shared__ __align__(16) unsigned short sA[2560 * 8];
    __shared__ int scnt[NM];
    __shared__ int scsr[NM * MAXL];      // 12288 B
    float (*phone)[257] = (float (*)[257])sA;

    const int tid  = threadIdx.x;
    const int lane = tid & 63;
    const int wv   = tid >> 6;          // 0..7 = column group (32 cols each)
    const int m16  = lane & 15;
    const int quad = lane >> 4;
    const int row0 = blockIdx.x * MBLK;

    // ---- issue csr/cnt FIRST (oldest in vmcnt queue -> their LDS stash waits
    // only on themselves, ~L2 latency, never on enc/B)
    int creg[6];
    #pragma unroll
    for (int j = 0; j < 6; ++j) creg[j] = csr[tid + j * 512];
    int cc = (tid < NM) ? cnt[tid] : 0;

    // ---- enc loads, k-split halves: half h = 32 rows x fp32 k in [h*320,(h+1)*320)
    float4 areg0[5], areg1[5];
    #pragma unroll
    for (int i = 0; i < 5; ++i) {
        int G = i * 8192 + tid * 16;
        int row = G / 1280;
        int cb4 = (G - row * 1280) >> 2;     // fp32 col within half, 0..319
        areg0[i] = *(const float4*)(enc + (size_t)(row0 + row) * NH + cb4);
    }
    #pragma unroll
    for (int i = 0; i < 5; ++i) {
        int G = i * 8192 + tid * 16;
        int row = G / 1280;
        int cb4 = (G - row * 1280) >> 2;
        areg1[i] = *(const float4*)(enc + (size_t)(row0 + row) * NH + 320 + cb4);
    }

    // ---- full B prefetch, steps 0..19 (L2-resident wsB2); 160 VGPR, fits at
    // the 256 cap from __launch_bounds__(512,1) -> no scratch spill.
    const unsigned short* bptr = wsB2 + ((size_t)(wv * 2) * 64 + lane) * 8;
    uint4 bpre[2 * NSTEP];
    #pragma unroll
    for (int s = 0; s < NSTEP; ++s) {
        bpre[2 * s + 0] = *(const uint4*)(bptr + ((size_t)s * 16 + 0) * 64 * 8);
        bpre[2 * s + 1] = *(const uint4*)(bptr + ((size_t)s * 16 + 1) * 64 * 8);
    }

    // ---- stash csr/cnt to LDS (waits only the oldest loads)
    #pragma unroll
    for (int j = 0; j < 6; ++j) scsr[tid + j * 512] = creg[j];
    if (tid < NM) scnt[tid] = cc;

    // ---- convert + store half0 (register dep waits enc-half0 retire only;
    // half1 + B stay in flight)
    #pragma unroll
    for (int i = 0; i < 5; ++i) {
        int G = i * 8192 + tid * 16;
        int row = G / 1280;
        int cb4 = (G - row * 1280) >> 2;
        int k = cb4;                     // half 0
        int s  = k >> 5;
        int q  = (k & 31) >> 3;
        int j0 = k & 7;                  // 0 or 4
        unsigned short v[4];
        v[0] = f2b(areg0[i].x); v[1] = f2b(areg0[i].y);
        v[2] = f2b(areg0[i].z); v[3] = f2b(areg0[i].w);
        int soff = ((s * 2 + (row >> 4)) * 64 + q * 16 + (row & 15)) * 8 + j0;
        *(uint2*)(sA + soff) = *(const uint2*)v;
    }
    lds_barrier();           // lgkmcnt only -- enc-half1 still in flight

    floatx4 acc00 = {0.f,0.f,0.f,0.f}, acc01 = acc00, acc10 = acc00, acc11 = acc00;
    const unsigned short* aptr = sA + (size_t)lane * 8;

    // ---- K-steps 0..9 on half0 (overlaps enc-half1 HBM arrival)
    #pragma unroll
    for (int s = 0; s < 10; ++s) {
        uint4 a0 = *(const uint4*)(aptr + (size_t)(s * 2 + 0) * 64 * 8);
        uint4 a1 = *(const uint4*)(aptr + (size_t)(s * 2 + 1) * 64 * 8);
        bf16x8 A0 = __builtin_bit_cast(bf16x8, a0);
        bf16x8 A1 = __builtin_bit_cast(bf16x8, a1);
        bf16x8 B0 = __builtin_bit_cast(bf16x8, bpre[2 * s + 0]);
        bf16x8 B1 = __builtin_bit_cast(bf16x8, bpre[2 * s + 1]);
        acc00 = __builtin_amdgcn_mfma_f32_16x16x32_bf16(A0, B0, acc00, 0, 0, 0);
        acc01 = __builtin_amdgcn_mfma_f32_16x16x32_bf16(A0, B1, acc01, 0, 0, 0);
        acc10 = __builtin_amdgcn_mfma_f32_16x16x32_bf16(A1, B0, acc10, 0, 0, 0);
        acc11 = __builtin_amdgcn_mfma_f32_16x16x32_bf16(A1, B1, acc11, 0, 0, 0);
    }

    // ---- convert + store half1 (register dep waits enc-half1 only)
    #pragma unroll
    for (int i = 0; i < 5; ++i) {
        int G = i * 8192 + tid * 16;
        int row = G / 1280;
        int cb4 = (G - row * 1280) >> 2;
        int k = 320 + cb4;               // half 1
        int s  = k >> 5;
        int q  = (k & 31) >> 3;
        int j0 = k & 7;
        unsigned short v[4];
        v[0] = f2b(areg1[i].x); v[1] = f2b(areg1[i].y);
        v[2] = f2b(areg1[i].z); v[3] = f2b(areg1[i].w);
        int soff = ((s * 2 + (row >> 4)) * 64 + q * 16 + (row & 15)) * 8 + j0;
        *(uint2*)(sA + soff) = *(const uint2*)v;
    }
    lds_barrier();

    // ---- K-steps 10..19 on half1
    #pragma unroll
    for (int s = 10; s < NSTEP; ++s) {
        uint4 a0 = *(const uint4*)(aptr + (size_t)(s * 2 + 0) * 64 * 8);
        uint4 a1 = *(const uint4*)(aptr + (size_t)(s * 2 + 1) * 64 * 8);
        bf16x8 A0 = __builtin_bit_cast(bf16x8, a0);
        bf16x8 A1 = __builtin_bit_cast(bf16x8, a1);
        bf16x8 B0 = __builtin_bit_cast(bf16x8, bpre[2 * s + 0]);
        bf16x8 B1 = __builtin_bit_cast(bf16x8, bpre[2 * s + 1]);
        acc00 = __builtin_amdgcn_mfma_f32_16x16x32_bf16(A0, B0, acc00, 0, 0, 0);
        acc01 = __builtin_amdgcn_mfma_f32_16x16x32_bf16(A0, B1, acc01, 0, 0, 0);
        acc10 = __builtin_amdgcn_mfma_f32_16x16x32_bf16(A1, B0, acc10, 0, 0, 0);
        acc11 = __builtin_amdgcn_mfma_f32_16x16x32_bf16(A1, B1, acc11, 0, 0, 0);
    }

    __syncthreads();   // A-LDS fully consumed; safe to overwrite with phone[][]

    // C/D layout: col = lane&15, row = quad*4 + reg
    const float scale = 0.03952847075210474f;  // 1/sqrt(640)
    #pragma unroll
    for (int i = 0; i < 4; ++i) {
        int r = quad * 4 + i;
        phone[r     ][wv * 32 +  0 + m16] = acc00[i] * scale;
        phone[r     ][wv * 32 + 16 + m16] = acc01[i] * scale;
        phone[r + 16][wv * 32 +  0 + m16] = acc10[i] * scale;
        phone[r + 16][wv * 32 + 16 + m16] = acc11[i] * scale;
    }
    __syncthreads();

    // ---- seg-max + log_softmax: 16 threads per row (512 = 32 rows x 16)
    const int r   = tid >> 4;
    const int l16 = tid & 15;
    float pmv[6];
    float mx = -INFINITY;
    #pragma unroll
    for (int j = 0; j < 6; ++j) {
        int m = l16 + j * 16;
        int c = scnt[m];
        const int* lst = scsr + m * MAXL;
        float best = -INFINITY;
        for (int jj = 0; jj < c; ++jj) best = fmaxf(best, phone[r][lst[jj]]);
        pmv[j] = best;
        mx = fmaxf(mx, best);
    }
    #pragma unroll
    for (int d = 1; d < 16; d <<= 1) mx = fmaxf(mx, __shfl_xor(mx, d));
    float s = 0.f;
    #pragma unroll
    for (int j = 0; j < 6; ++j) s += __expf(pmv[j] - mx);
    #pragma unroll
    for (int d = 1; d < 16; d <<= 1) s += __shfl_xor(s, d);
    const float lse = mx + __logf(s);
    #pragma unroll
    for (int j = 0; j < 6; ++j)
        out[(size_t)(row0 + r) * NM + l16 + j * 16] = pmv[j] - lse;
}

extern "C" void kernel_launch(void* const* d_in, const int* in_sizes, int n_in,
                              void* d_out, int out_size, void* d_ws, size_t ws_size,
                              hipStream_t stream) {
    const float* enc     = (const float*)d_in[0];   // (8,1024,640) f32
    const float* f2p     = (const float*)d_in[1];   // (640,230) f32
    const float* mapping = (const float*)d_in[2];   // (96,230) f32
    float* out = (float*)d_out;                     // (8,1024,96) f32

    char* ws = (char*)d_ws;
    int* cnt = (int*)(ws + OFF_CNT);
    int* csr = (int*)(ws + OFF_CSR);
    unsigned short* wsB2 = (unsigned short*)(ws + OFF_B);

    prep_kernel<<<104, 256, 0, stream>>>(f2p, mapping, cnt, csr, wsB2);
    fused_phonetics_kernel<<<NBLOCKS, 512, 0, stream>>>(enc, wsB2, cnt, csr, out);
}